// Round 2
// baseline (475.131 us; speedup 1.0000x reference)
//
#include <hip/hip_runtime.h>
#include <hip/hip_bf16.h>

// Problem constants (B=4, S=4096, D=4096, r=4, COFF=2, HD=512)
#define D_DIM 4096
#define OD    1024          // COFF*HD combined projection width
#define M_TOT 16384         // B*S
#define N_TOT 2048          // 2*OD (kv/gate interleaved)
#define BM 128
#define BN 128
#define BK 64

#define GLOBAL_AS __attribute__((address_space(1)))
#define LDS_AS    __attribute__((address_space(3)))

typedef __attribute__((ext_vector_type(8))) short          bf16x8;
typedef __attribute__((ext_vector_type(8))) unsigned short u16x8;
typedef __attribute__((ext_vector_type(4))) float          f32x4;

__device__ __forceinline__ unsigned short f2bf(float f) {
    unsigned int u = __float_as_uint(f);
    u = (u + 0x7fffu + ((u >> 16) & 1u)) >> 16;
    return (unsigned short)u;
}

__device__ __forceinline__ float sigm(float x) {
    return 1.0f / (1.0f + __expf(-x));
}

__device__ __forceinline__ void gload16(const void* g, void* l) {
    // HBM -> LDS direct, 16 B per lane; LDS dest = wave-uniform base + lane*16
    __builtin_amdgcn_global_load_lds((const GLOBAL_AS void*)g, (LDS_AS void*)l, 16, 0, 0);
}

// ---- prep: interleave wkv/wgate rows into combined bf16 weight [2048][4096]
__global__ void prep_weights(const float* __restrict__ wkv,
                             const float* __restrict__ wgate,
                             unsigned short* __restrict__ Wc) {
    int t  = blockIdx.x * 256 + threadIdx.x;   // 2048 * 512 threads
    int n  = t >> 9;                           // combined row: o = n>>1, gate = n&1
    int k8 = t & 511;                          // 8-element chunk in row
    const float* src = (n & 1) ? wgate : wkv;
    const float4* s4 = (const float4*)(src + (size_t)(n >> 1) * D_DIM + k8 * 8);
    float4 a = s4[0], b = s4[1];
    u16x8 o;
    o[0] = f2bf(a.x); o[1] = f2bf(a.y); o[2] = f2bf(a.z); o[3] = f2bf(a.w);
    o[4] = f2bf(b.x); o[5] = f2bf(b.y); o[6] = f2bf(b.z); o[7] = f2bf(b.w);
    *(u16x8*)(Wc + (size_t)n * D_DIM + k8 * 8) = o;
}

// ---- prep: x fp32 -> bf16
__global__ void prep_x(const float* __restrict__ x, unsigned short* __restrict__ xb) {
    size_t t = (size_t)blockIdx.x * 256 + threadIdx.x;  // 8,388,608 threads * 8 elems
    const float4* s = (const float4*)(x + t * 8);
    float4 a = s[0], b = s[1];
    u16x8 o;
    o[0] = f2bf(a.x); o[1] = f2bf(a.y); o[2] = f2bf(a.z); o[3] = f2bf(a.w);
    o[4] = f2bf(b.x); o[5] = f2bf(b.y); o[6] = f2bf(b.z); o[7] = f2bf(b.w);
    *(u16x8*)(xb + t * 8) = o;
}

// ---- prep: ape mean over the 4 window positions
__global__ void prep_ape(const float* __restrict__ ape, float* __restrict__ am) {
    int t = blockIdx.x * 256 + threadIdx.x;
    if (t < OD)
        am[t] = 0.25f * (ape[t] + ape[OD + t] + ape[2 * OD + t] + ape[3 * OD + t]);
}

// =====================================================================
// Main fused GEMM (gload_lds path): C = xb @ Wc^T, gate, +ape, window-mean.
// Linear LDS layout [128][64] (no swizzle: global_load_lds writes linearly;
// 16-way ds_read conflicts are hidden at a 2-phase schedule, m233).
// =====================================================================
__global__ __launch_bounds__(256)
void gemm_fused_gl(const unsigned short* __restrict__ A,
                   const unsigned short* __restrict__ Wc,
                   const float* __restrict__ ape_mean,
                   float* __restrict__ out_pooled) {
    __shared__ __align__(16) unsigned short As[BM * BK];
    __shared__ __align__(16) unsigned short Bs[BN * BK];

    const int tid  = threadIdx.x;
    const int lane = tid & 63;
    const int wave = tid >> 6;           // 4 waves, 2x2 over the 128x128 tile
    const int wr   = wave >> 1;
    const int wc   = wave & 1;
    const int n0   = blockIdx.x * BN;
    const int m0   = blockIdx.y * BM;
    const int h    = lane & 15;
    const int q    = lane >> 4;

    // staging geometry: wave w owns rows [w*32, w*32+32); call i covers 8 rows.
    // lane l -> row offset (l>>3), 16B chunk (l&7). LDS dest = base + lane*16 (linear).
    const int srow = wave * 32 + (lane >> 3);
    const int sc8  = lane & 7;
    const unsigned short* Ag = A  + (size_t)(m0 + srow) * D_DIM + sc8 * 8;
    const unsigned short* Bg = Wc + (size_t)(n0 + srow) * D_DIM + sc8 * 8;
    unsigned short* AsW = As + wave * 2048;   // wave's 32-row slab (32*64 elems)
    unsigned short* BsW = Bs + wave * 2048;

    f32x4 acc[4][4];
    const f32x4 z = {0.f, 0.f, 0.f, 0.f};
#pragma unroll
    for (int i = 0; i < 4; ++i)
#pragma unroll
        for (int j = 0; j < 4; ++j) acc[i][j] = z;

    for (int kt = 0; kt < D_DIM; kt += BK) {
#pragma unroll
        for (int i = 0; i < 4; ++i)
            gload16(Ag + kt + (size_t)(i * 8) * D_DIM, AsW + i * 512);
#pragma unroll
        for (int i = 0; i < 4; ++i)
            gload16(Bg + kt + (size_t)(i * 8) * D_DIM, BsW + i * 512);
        __syncthreads();   // compiler emits vmcnt(0) drain before s_barrier

#pragma unroll
        for (int ks = 0; ks < 2; ++ks) {
            const int kb = ks * 32 + q * 8;
            bf16x8 af[4], bfr[4];
#pragma unroll
            for (int am = 0; am < 4; ++am)
                af[am] = *(const bf16x8*)&As[(wr * 64 + am * 16 + h) * BK + kb];
#pragma unroll
            for (int bn = 0; bn < 4; ++bn)
                bfr[bn] = *(const bf16x8*)&Bs[(wc * 64 + bn * 16 + h) * BK + kb];
#pragma unroll
            for (int am = 0; am < 4; ++am)
#pragma unroll
                for (int bn = 0; bn < 4; ++bn)
                    acc[am][bn] = __builtin_amdgcn_mfma_f32_16x16x32_bf16(
                        af[am], bfr[bn], acc[am][bn], 0, 0, 0);
        }
        __syncthreads();
    }

    // Epilogue: even combined-cols = kv, odd = gate (adjacent lanes).
    // Lane's 4 acc regs = rows q*4..q*4+3 = one r=4 pooling window.
    const bool is_kv = ((h & 1) == 0);
#pragma unroll
    for (int am = 0; am < 4; ++am) {
        const int mbase = m0 + wr * 64 + am * 16 + q * 4;
        const int wglob = mbase >> 2;
#pragma unroll
        for (int bn = 0; bn < 4; ++bn) {
            f32x4 kv = acc[am][bn];
            float g0 = __shfl_xor(kv[0], 1);
            float g1 = __shfl_xor(kv[1], 1);
            float g2 = __shfl_xor(kv[2], 1);
            float g3 = __shfl_xor(kv[3], 1);
            if (is_kv) {
                float s = kv[0] * sigm(g0) + kv[1] * sigm(g1) +
                          kv[2] * sigm(g2) + kv[3] * sigm(g3);
                int n = n0 + wc * 64 + bn * 16 + h;   // even
                int o = n >> 1;
                out_pooled[(size_t)wglob * OD + o] = 0.25f * s + ape_mean[o];
            }
        }
    }
}

// ---- fallback (ws too small for xb): fp32 A + reg staging + XOR swizzle
__global__ __launch_bounds__(256)
void gemm_fused_f32(const float* __restrict__ Aptr,
                    const unsigned short* __restrict__ Wc,
                    const float* __restrict__ ape_mean,
                    float* __restrict__ out_pooled) {
    __shared__ __align__(16) unsigned short As[BM * BK];
    __shared__ __align__(16) unsigned short Bs[BN * BK];
    const int tid  = threadIdx.x;
    const int lane = tid & 63;
    const int wave = tid >> 6;
    const int wr   = wave >> 1;
    const int wc   = wave & 1;
    const int n0   = blockIdx.x * BN;
    const int m0   = blockIdx.y * BM;
    const int h    = lane & 15;
    const int q    = lane >> 4;

    f32x4 acc[4][4];
    const f32x4 z = {0.f, 0.f, 0.f, 0.f};
#pragma unroll
    for (int i = 0; i < 4; ++i)
#pragma unroll
        for (int j = 0; j < 4; ++j) acc[i][j] = z;

    for (int kt = 0; kt < D_DIM; kt += BK) {
#pragma unroll
        for (int i = 0; i < 4; ++i) {
            int chunk = tid + i * 256;
            int row = chunk >> 3, c8 = chunk & 7;
            int dst = (row * BK + c8 * 8) ^ ((row & 7) << 3);
            const float4* s = (const float4*)(Aptr + (size_t)(m0 + row) * D_DIM + kt + c8 * 8);
            float4 a = s[0], b = s[1];
            u16x8 o;
            o[0] = f2bf(a.x); o[1] = f2bf(a.y); o[2] = f2bf(a.z); o[3] = f2bf(a.w);
            o[4] = f2bf(b.x); o[5] = f2bf(b.y); o[6] = f2bf(b.z); o[7] = f2bf(b.w);
            *(u16x8*)&As[dst] = o;
        }
#pragma unroll
        for (int i = 0; i < 4; ++i) {
            int chunk = tid + i * 256;
            int row = chunk >> 3, c8 = chunk & 7;
            int dst = (row * BK + c8 * 8) ^ ((row & 7) << 3);
            *(u16x8*)&Bs[dst] =
                *(const u16x8*)(Wc + (size_t)(n0 + row) * D_DIM + kt + c8 * 8);
        }
        __syncthreads();
#pragma unroll
        for (int ks = 0; ks < 2; ++ks) {
            const int kb = ks * 32 + q * 8;
            bf16x8 af[4], bfr[4];
#pragma unroll
            for (int am = 0; am < 4; ++am) {
                int row = wr * 64 + am * 16 + h;
                af[am] = *(const bf16x8*)&As[(row * BK + kb) ^ ((row & 7) << 3)];
            }
#pragma unroll
            for (int bn = 0; bn < 4; ++bn) {
                int row = wc * 64 + bn * 16 + h;
                bfr[bn] = *(const bf16x8*)&Bs[(row * BK + kb) ^ ((row & 7) << 3)];
            }
#pragma unroll
            for (int am = 0; am < 4; ++am)
#pragma unroll
                for (int bn = 0; bn < 4; ++bn)
                    acc[am][bn] = __builtin_amdgcn_mfma_f32_16x16x32_bf16(
                        af[am], bfr[bn], acc[am][bn], 0, 0, 0);
        }
        __syncthreads();
    }
    const bool is_kv = ((h & 1) == 0);
#pragma unroll
    for (int am = 0; am < 4; ++am) {
        const int mbase = m0 + wr * 64 + am * 16 + q * 4;
        const int wglob = mbase >> 2;
#pragma unroll
        for (int bn = 0; bn < 4; ++bn) {
            f32x4 kv = acc[am][bn];
            float g0 = __shfl_xor(kv[0], 1);
            float g1 = __shfl_xor(kv[1], 1);
            float g2 = __shfl_xor(kv[2], 1);
            float g3 = __shfl_xor(kv[3], 1);
            if (is_kv) {
                float s = kv[0] * sigm(g0) + kv[1] * sigm(g1) +
                          kv[2] * sigm(g2) + kv[3] * sigm(g3);
                int n = n0 + wc * 64 + bn * 16 + h;
                int o = n >> 1;
                out_pooled[(size_t)wglob * OD + o] = 0.25f * s + ape_mean[o];
            }
        }
    }
}

// ---- in-place RMSNorm over head_dim=512 per token (8192 tokens)
__global__ void rmsnorm_inplace(float* __restrict__ out, const float* __restrict__ nw) {
    int token = blockIdx.x * 4 + (threadIdx.x >> 6);   // one wave per token
    int lane  = threadIdx.x & 63;
    float4* p = (float4*)(out + (size_t)token * 512);
    float4 v0 = p[lane * 2], v1 = p[lane * 2 + 1];
    float ss = v0.x * v0.x + v0.y * v0.y + v0.z * v0.z + v0.w * v0.w +
               v1.x * v1.x + v1.y * v1.y + v1.z * v1.z + v1.w * v1.w;
#pragma unroll
    for (int off = 32; off > 0; off >>= 1) ss += __shfl_xor(ss, off);
    float rs = rsqrtf(ss * (1.0f / 512.0f) + 1e-6f);
    const float4* w4 = (const float4*)nw;
    float4 w0 = w4[lane * 2], w1 = w4[lane * 2 + 1];
    float4 r0, r1;
    r0.x = v0.x * rs * w0.x; r0.y = v0.y * rs * w0.y;
    r0.z = v0.z * rs * w0.z; r0.w = v0.w * rs * w0.w;
    r1.x = v1.x * rs * w1.x; r1.y = v1.y * rs * w1.y;
    r1.z = v1.z * rs * w1.z; r1.w = v1.w * rs * w1.w;
    p[lane * 2]     = r0;
    p[lane * 2 + 1] = r1;
}

extern "C" void kernel_launch(void* const* d_in, const int* in_sizes, int n_in,
                              void* d_out, int out_size, void* d_ws, size_t ws_size,
                              hipStream_t stream) {
    const float* x     = (const float*)d_in[0];
    const float* wkv   = (const float*)d_in[1];
    const float* wgate = (const float*)d_in[2];
    const float* ape   = (const float*)d_in[3];
    const float* normw = (const float*)d_in[4];
    float* out = (float*)d_out;

    unsigned short* Wc  = (unsigned short*)d_ws;
    float* ape_mean     = (float*)((char*)d_ws + (size_t)16 * 1024 * 1024);
    unsigned short* xb  = (unsigned short*)((char*)d_ws + (size_t)16 * 1024 * 1024 + 65536);
    const size_t need_xb = (size_t)16 * 1024 * 1024 + 65536 + (size_t)M_TOT * D_DIM * 2;
    const bool use_xb = (ws_size >= need_xb);

    prep_weights<<<4096, 256, 0, stream>>>(wkv, wgate, Wc);
    prep_ape<<<4, 256, 0, stream>>>(ape, ape_mean);

    if (use_xb) {
        prep_x<<<32768, 256, 0, stream>>>(x, xb);
        gemm_fused_gl<<<dim3(N_TOT / BN, M_TOT / BM), 256, 0, stream>>>(
            xb, Wc, ape_mean, out);
    } else {
        gemm_fused_f32<<<dim3(N_TOT / BN, M_TOT / BM), 256, 0, stream>>>(
            x, Wc, ape_mean, out);
    }

    rmsnorm_inplace<<<2048, 256, 0, stream>>>(out, normw);
}

// Round 3
// 386.836 us; speedup vs baseline: 1.2282x; 1.2282x over previous
//
#include <hip/hip_runtime.h>
#include <hip/hip_bf16.h>

// Problem constants (B=4, S=4096, D=4096, r=4, COFF=2, HD=512)
#define D_DIM 4096
#define OD    1024          // COFF*HD combined projection width
#define M_TOT 16384         // B*S
#define N_TOT 2048          // 2*OD (kv/gate interleaved)
#define BM 128
#define BN 128
#define BK 64

#define GLOBAL_AS __attribute__((address_space(1)))
#define LDS_AS    __attribute__((address_space(3)))

typedef __attribute__((ext_vector_type(8))) short          bf16x8;
typedef __attribute__((ext_vector_type(8))) unsigned short u16x8;
typedef __attribute__((ext_vector_type(4))) float          f32x4;

__device__ __forceinline__ unsigned short f2bf(float f) {
    unsigned int u = __float_as_uint(f);
    u = (u + 0x7fffu + ((u >> 16) & 1u)) >> 16;
    return (unsigned short)u;
}

__device__ __forceinline__ float sigm(float x) {
    return 1.0f / (1.0f + __expf(-x));
}

__device__ __forceinline__ void gload16(const void* g, void* l) {
    // HBM -> LDS direct, 16 B per lane; LDS dest = wave-uniform base + lane*16 (linear)
    __builtin_amdgcn_global_load_lds((const GLOBAL_AS void*)g, (LDS_AS void*)l, 16, 0, 0);
}

// ---- prep: interleave wkv/wgate rows into combined bf16 weight [2048][4096]
__global__ void prep_weights(const float* __restrict__ wkv,
                             const float* __restrict__ wgate,
                             unsigned short* __restrict__ Wc) {
    int t  = blockIdx.x * 256 + threadIdx.x;   // 2048 * 512 threads
    int n  = t >> 9;                           // combined row: o = n>>1, gate = n&1
    int k8 = t & 511;                          // 8-element chunk in row
    const float* src = (n & 1) ? wgate : wkv;
    const float4* s4 = (const float4*)(src + (size_t)(n >> 1) * D_DIM + k8 * 8);
    float4 a = s4[0], b = s4[1];
    u16x8 o;
    o[0] = f2bf(a.x); o[1] = f2bf(a.y); o[2] = f2bf(a.z); o[3] = f2bf(a.w);
    o[4] = f2bf(b.x); o[5] = f2bf(b.y); o[6] = f2bf(b.z); o[7] = f2bf(b.w);
    *(u16x8*)(Wc + (size_t)n * D_DIM + k8 * 8) = o;
}

// ---- prep: x fp32 -> bf16
__global__ void prep_x(const float* __restrict__ x, unsigned short* __restrict__ xb) {
    size_t t = (size_t)blockIdx.x * 256 + threadIdx.x;  // 8,388,608 threads * 8 elems
    const float4* s = (const float4*)(x + t * 8);
    float4 a = s[0], b = s[1];
    u16x8 o;
    o[0] = f2bf(a.x); o[1] = f2bf(a.y); o[2] = f2bf(a.z); o[3] = f2bf(a.w);
    o[4] = f2bf(b.x); o[5] = f2bf(b.y); o[6] = f2bf(b.z); o[7] = f2bf(b.w);
    *(u16x8*)(xb + t * 8) = o;
}

// ---- prep: ape mean over the 4 window positions
__global__ void prep_ape(const float* __restrict__ ape, float* __restrict__ am) {
    int t = blockIdx.x * 256 + threadIdx.x;
    if (t < OD)
        am[t] = 0.25f * (ape[t] + ape[OD + t] + ape[2 * OD + t] + ape[3 * OD + t]);
}

// =====================================================================
// Main fused GEMM: global_load_lds staging with PRE-SWIZZLED global source
// (rule 21 both-sides pattern): LDS dest linear, source chunk index XOR'd,
// ds_read applies the same XOR -> round-1's zero-conflict read pattern.
// =====================================================================
__global__ __launch_bounds__(256)
void gemm_fused_gl(const unsigned short* __restrict__ A,
                   const unsigned short* __restrict__ Wc,
                   const float* __restrict__ ape_mean,
                   float* __restrict__ out_pooled) {
    __shared__ __align__(16) unsigned short As[BM * BK];
    __shared__ __align__(16) unsigned short Bs[BN * BK];

    const int tid  = threadIdx.x;
    const int lane = tid & 63;
    const int wave = tid >> 6;           // 4 waves, 2x2 over the 128x128 tile
    const int wr   = wave >> 1;
    const int wc   = wave & 1;
    const int n0   = blockIdx.x * BN;
    const int m0   = blockIdx.y * BM;
    const int h    = lane & 15;
    const int q    = lane >> 4;

    // staging geometry: wave w owns rows [w*32, w*32+32); issue i covers 8 rows.
    // lane l -> row offset (l>>3); SOURCE 16B-chunk index is pre-swizzled:
    //   sc8 = (l&7) ^ ((l>>3)&7)   (row&7 == (l>>3)&7 for every issue)
    // so that linear LDS dest (base + l*16) receives the swizzled layout.
    const int srow = wave * 32 + (lane >> 3);
    const int sc8  = (lane & 7) ^ ((lane >> 3) & 7);
    const unsigned short* Ag = A  + (size_t)(m0 + srow) * D_DIM + sc8 * 8;
    const unsigned short* Bg = Wc + (size_t)(n0 + srow) * D_DIM + sc8 * 8;
    unsigned short* AsW = As + wave * 2048;   // wave's 32-row slab (32*64 elems)
    unsigned short* BsW = Bs + wave * 2048;

    f32x4 acc[4][4];
    const f32x4 z = {0.f, 0.f, 0.f, 0.f};
#pragma unroll
    for (int i = 0; i < 4; ++i)
#pragma unroll
        for (int j = 0; j < 4; ++j) acc[i][j] = z;

    for (int kt = 0; kt < D_DIM; kt += BK) {
#pragma unroll
        for (int i = 0; i < 4; ++i)
            gload16(Ag + kt + (size_t)(i * 8) * D_DIM, AsW + i * 512);
#pragma unroll
        for (int i = 0; i < 4; ++i)
            gload16(Bg + kt + (size_t)(i * 8) * D_DIM, BsW + i * 512);
        __syncthreads();   // compiler emits vmcnt(0) drain before s_barrier

#pragma unroll
        for (int ks = 0; ks < 2; ++ks) {
            const int kb = ks * 32 + q * 8;
            bf16x8 af[4], bfr[4];
#pragma unroll
            for (int am = 0; am < 4; ++am) {
                int row = wr * 64 + am * 16 + h;
                af[am] = *(const bf16x8*)&As[(row * BK + kb) ^ ((row & 7) << 3)];
            }
#pragma unroll
            for (int bn = 0; bn < 4; ++bn) {
                int row = wc * 64 + bn * 16 + h;
                bfr[bn] = *(const bf16x8*)&Bs[(row * BK + kb) ^ ((row & 7) << 3)];
            }
#pragma unroll
            for (int am = 0; am < 4; ++am)
#pragma unroll
                for (int bn = 0; bn < 4; ++bn)
                    acc[am][bn] = __builtin_amdgcn_mfma_f32_16x16x32_bf16(
                        af[am], bfr[bn], acc[am][bn], 0, 0, 0);
        }
        __syncthreads();
    }

    // Epilogue: even combined-cols = kv, odd = gate (adjacent lanes).
    // Lane's 4 acc regs = rows q*4..q*4+3 = one r=4 pooling window.
    const bool is_kv = ((h & 1) == 0);
#pragma unroll
    for (int am = 0; am < 4; ++am) {
        const int mbase = m0 + wr * 64 + am * 16 + q * 4;
        const int wglob = mbase >> 2;
#pragma unroll
        for (int bn = 0; bn < 4; ++bn) {
            f32x4 kv = acc[am][bn];
            float g0 = __shfl_xor(kv[0], 1);
            float g1 = __shfl_xor(kv[1], 1);
            float g2 = __shfl_xor(kv[2], 1);
            float g3 = __shfl_xor(kv[3], 1);
            if (is_kv) {
                float s = kv[0] * sigm(g0) + kv[1] * sigm(g1) +
                          kv[2] * sigm(g2) + kv[3] * sigm(g3);
                int n = n0 + wc * 64 + bn * 16 + h;   // even
                int o = n >> 1;
                out_pooled[(size_t)wglob * OD + o] = 0.25f * s + ape_mean[o];
            }
        }
    }
}

// ---- fallback (ws too small for xb): fp32 A + reg staging + XOR swizzle
__global__ __launch_bounds__(256)
void gemm_fused_f32(const float* __restrict__ Aptr,
                    const unsigned short* __restrict__ Wc,
                    const float* __restrict__ ape_mean,
                    float* __restrict__ out_pooled) {
    __shared__ __align__(16) unsigned short As[BM * BK];
    __shared__ __align__(16) unsigned short Bs[BN * BK];
    const int tid  = threadIdx.x;
    const int lane = tid & 63;
    const int wave = tid >> 6;
    const int wr   = wave >> 1;
    const int wc   = wave & 1;
    const int n0   = blockIdx.x * BN;
    const int m0   = blockIdx.y * BM;
    const int h    = lane & 15;
    const int q    = lane >> 4;

    f32x4 acc[4][4];
    const f32x4 z = {0.f, 0.f, 0.f, 0.f};
#pragma unroll
    for (int i = 0; i < 4; ++i)
#pragma unroll
        for (int j = 0; j < 4; ++j) acc[i][j] = z;

    for (int kt = 0; kt < D_DIM; kt += BK) {
#pragma unroll
        for (int i = 0; i < 4; ++i) {
            int chunk = tid + i * 256;
            int row = chunk >> 3, c8 = chunk & 7;
            int dst = (row * BK + c8 * 8) ^ ((row & 7) << 3);
            const float4* s = (const float4*)(Aptr + (size_t)(m0 + row) * D_DIM + kt + c8 * 8);
            float4 a = s[0], b = s[1];
            u16x8 o;
            o[0] = f2bf(a.x); o[1] = f2bf(a.y); o[2] = f2bf(a.z); o[3] = f2bf(a.w);
            o[4] = f2bf(b.x); o[5] = f2bf(b.y); o[6] = f2bf(b.z); o[7] = f2bf(b.w);
            *(u16x8*)&As[dst] = o;
        }
#pragma unroll
        for (int i = 0; i < 4; ++i) {
            int chunk = tid + i * 256;
            int row = chunk >> 3, c8 = chunk & 7;
            int dst = (row * BK + c8 * 8) ^ ((row & 7) << 3);
            *(u16x8*)&Bs[dst] =
                *(const u16x8*)(Wc + (size_t)(n0 + row) * D_DIM + kt + c8 * 8);
        }
        __syncthreads();
#pragma unroll
        for (int ks = 0; ks < 2; ++ks) {
            const int kb = ks * 32 + q * 8;
            bf16x8 af[4], bfr[4];
#pragma unroll
            for (int am = 0; am < 4; ++am) {
                int row = wr * 64 + am * 16 + h;
                af[am] = *(const bf16x8*)&As[(row * BK + kb) ^ ((row & 7) << 3)];
            }
#pragma unroll
            for (int bn = 0; bn < 4; ++bn) {
                int row = wc * 64 + bn * 16 + h;
                bfr[bn] = *(const bf16x8*)&Bs[(row * BK + kb) ^ ((row & 7) << 3)];
            }
#pragma unroll
            for (int am = 0; am < 4; ++am)
#pragma unroll
                for (int bn = 0; bn < 4; ++bn)
                    acc[am][bn] = __builtin_amdgcn_mfma_f32_16x16x32_bf16(
                        af[am], bfr[bn], acc[am][bn], 0, 0, 0);
        }
        __syncthreads();
    }
    const bool is_kv = ((h & 1) == 0);
#pragma unroll
    for (int am = 0; am < 4; ++am) {
        const int mbase = m0 + wr * 64 + am * 16 + q * 4;
        const int wglob = mbase >> 2;
#pragma unroll
        for (int bn = 0; bn < 4; ++bn) {
            f32x4 kv = acc[am][bn];
            float g0 = __shfl_xor(kv[0], 1);
            float g1 = __shfl_xor(kv[1], 1);
            float g2 = __shfl_xor(kv[2], 1);
            float g3 = __shfl_xor(kv[3], 1);
            if (is_kv) {
                float s = kv[0] * sigm(g0) + kv[1] * sigm(g1) +
                          kv[2] * sigm(g2) + kv[3] * sigm(g3);
                int n = n0 + wc * 64 + bn * 16 + h;
                int o = n >> 1;
                out_pooled[(size_t)wglob * OD + o] = 0.25f * s + ape_mean[o];
            }
        }
    }
}

// ---- in-place RMSNorm over head_dim=512 per token (8192 tokens)
__global__ void rmsnorm_inplace(float* __restrict__ out, const float* __restrict__ nw) {
    int token = blockIdx.x * 4 + (threadIdx.x >> 6);   // one wave per token
    int lane  = threadIdx.x & 63;
    float4* p = (float4*)(out + (size_t)token * 512);
    float4 v0 = p[lane * 2], v1 = p[lane * 2 + 1];
    float ss = v0.x * v0.x + v0.y * v0.y + v0.z * v0.z + v0.w * v0.w +
               v1.x * v1.x + v1.y * v1.y + v1.z * v1.z + v1.w * v1.w;
#pragma unroll
    for (int off = 32; off > 0; off >>= 1) ss += __shfl_xor(ss, off);
    float rs = rsqrtf(ss * (1.0f / 512.0f) + 1e-6f);
    const float4* w4 = (const float4*)nw;
    float4 w0 = w4[lane * 2], w1 = w4[lane * 2 + 1];
    float4 r0, r1;
    r0.x = v0.x * rs * w0.x; r0.y = v0.y * rs * w0.y;
    r0.z = v0.z * rs * w0.z; r0.w = v0.w * rs * w0.w;
    r1.x = v1.x * rs * w1.x; r1.y = v1.y * rs * w1.y;
    r1.z = v1.z * rs * w1.z; r1.w = v1.w * rs * w1.w;
    p[lane * 2]     = r0;
    p[lane * 2 + 1] = r1;
}

extern "C" void kernel_launch(void* const* d_in, const int* in_sizes, int n_in,
                              void* d_out, int out_size, void* d_ws, size_t ws_size,
                              hipStream_t stream) {
    const float* x     = (const float*)d_in[0];
    const float* wkv   = (const float*)d_in[1];
    const float* wgate = (const float*)d_in[2];
    const float* ape   = (const float*)d_in[3];
    const float* normw = (const float*)d_in[4];
    float* out = (float*)d_out;

    unsigned short* Wc  = (unsigned short*)d_ws;
    float* ape_mean     = (float*)((char*)d_ws + (size_t)16 * 1024 * 1024);
    unsigned short* xb  = (unsigned short*)((char*)d_ws + (size_t)16 * 1024 * 1024 + 65536);
    const size_t need_xb = (size_t)16 * 1024 * 1024 + 65536 + (size_t)M_TOT * D_DIM * 2;
    const bool use_xb = (ws_size >= need_xb);

    prep_weights<<<4096, 256, 0, stream>>>(wkv, wgate, Wc);
    prep_ape<<<4, 256, 0, stream>>>(ape, ape_mean);

    if (use_xb) {
        prep_x<<<32768, 256, 0, stream>>>(x, xb);
        gemm_fused_gl<<<dim3(N_TOT / BN, M_TOT / BM), 256, 0, stream>>>(
            xb, Wc, ape_mean, out);
    } else {
        gemm_fused_f32<<<dim3(N_TOT / BN, M_TOT / BM), 256, 0, stream>>>(
            x, Wc, ape_mean, out);
    }

    rmsnorm_inplace<<<2048, 256, 0, stream>>>(out, normw);
}